// Round 1
// baseline (434.447 us; speedup 1.0000x reference)
//
#include <hip/hip_runtime.h>

#define NN 50000
#define EE 800000
#define HC 64

// ---------------------------------------------------------------------------
// Kernel 1: per-node linear layers + attention score
//   xh[n,c]  = b_lin[c]  + sum_k x[n,k]    * W_lin[c,k]     (k<128)
//   th       = b_topo[c] + sum_k topo[n,k] * W_topo[c,k]    (k<64)
//   s[n,h]   = lrelu( sum_c xh*att_node + th*att_topo )
// Block = 256 threads = 4 nodes x 64 channels. W staged in LDS (+1 pad).
// ---------------------------------------------------------------------------
__global__ __launch_bounds__(256) void node_stage_k(
    const float* __restrict__ x, const float* __restrict__ topo,
    const float* __restrict__ Wl, const float* __restrict__ bl,
    const float* __restrict__ Wt, const float* __restrict__ bt,
    const float* __restrict__ attn, const float* __restrict__ attt,
    float* __restrict__ xh, float* __restrict__ ls)
{
    __shared__ float WL[64][129];   // 33 KB, bank (c+k)%32 -> conflict-free
    __shared__ float WT[64][65];    // 16.6 KB
    int tid = threadIdx.x;
    for (int i = tid; i < 64 * 128; i += 256) WL[i >> 7][i & 127] = Wl[i];
    for (int i = tid; i < 64 * 64;  i += 256) WT[i >> 6][i & 63]  = Wt[i];
    __syncthreads();

    int idx = blockIdx.x * 256 + tid;
    if (idx >= NN * HC) return;
    int n = idx >> 6, cl = idx & 63, h = cl >> 5, cc = cl & 31;

    const float* xr = x + (long)n * 128;
    float xv = bl[cl];
#pragma unroll
    for (int k = 0; k < 128; ++k) xv = fmaf(WL[cl][k], xr[k], xv);

    const float* tr = topo + (long)n * 64;
    float tv = bt[cl];
#pragma unroll
    for (int k = 0; k < 64; ++k) tv = fmaf(WT[cl][k], tr[k], tv);

    xh[idx] = xv;

    float sc = xv * attn[h * 32 + cc] + tv * attt[h * 32 + cc];
#pragma unroll
    for (int d = 16; d >= 1; d >>= 1) sc += __shfl_xor(sc, d, 64); // 32-lane group reduce
    if (cc == 0) {
        ls[n * 2 + h] = sc > 0.f ? sc : 0.2f * sc;   // leaky_relu(0.2)
    }
}

// ---------------------------------------------------------------------------
// Kernel 2: degree histograms (row for CSR, col for softmax weighting)
// ---------------------------------------------------------------------------
__global__ __launch_bounds__(256) void count_k(
    const int* __restrict__ eidx,
    unsigned* __restrict__ cnt_row, unsigned* __restrict__ cnt_col)
{
    int e = blockIdx.x * 256 + threadIdx.x;
    if (e < EE) {
        atomicAdd(&cnt_row[eidx[e]], 1u);
        atomicAdd(&cnt_col[eidx[EE + e]], 1u);
    }
}

// ---------------------------------------------------------------------------
// Softmax statistics over edges, collapsed to node level:
//   max_h = max over n (cnt_col[n]>0) of ls[n,h]
//   denom_h = sum over n of cnt_col[n] * exp(ls[n,h]-max_h)
// ---------------------------------------------------------------------------
__global__ __launch_bounds__(256) void max_partial_k(
    const float* __restrict__ ls, const unsigned* __restrict__ cntc,
    float* __restrict__ part)
{
    float m0 = -INFINITY, m1 = -INFINITY;
    for (int i = blockIdx.x * 256 + threadIdx.x; i < NN; i += 256 * 256) {
        if (cntc[i]) {
            m0 = fmaxf(m0, ls[2 * i]);
            m1 = fmaxf(m1, ls[2 * i + 1]);
        }
    }
#pragma unroll
    for (int d = 32; d; d >>= 1) {
        m0 = fmaxf(m0, __shfl_xor(m0, d, 64));
        m1 = fmaxf(m1, __shfl_xor(m1, d, 64));
    }
    __shared__ float s[8];
    int w = threadIdx.x >> 6;
    if ((threadIdx.x & 63) == 0) { s[w * 2] = m0; s[w * 2 + 1] = m1; }
    __syncthreads();
    if (threadIdx.x == 0) {
        for (int j = 1; j < 4; ++j) { m0 = fmaxf(m0, s[j * 2]); m1 = fmaxf(m1, s[j * 2 + 1]); }
        part[blockIdx.x * 2] = m0; part[blockIdx.x * 2 + 1] = m1;
    }
}

__global__ __launch_bounds__(256) void max_final_k(const float* __restrict__ part,
                                                   float* __restrict__ gstat)
{
    float m0 = part[threadIdx.x * 2], m1 = part[threadIdx.x * 2 + 1];
#pragma unroll
    for (int d = 32; d; d >>= 1) {
        m0 = fmaxf(m0, __shfl_xor(m0, d, 64));
        m1 = fmaxf(m1, __shfl_xor(m1, d, 64));
    }
    __shared__ float s[8];
    int w = threadIdx.x >> 6;
    if ((threadIdx.x & 63) == 0) { s[w * 2] = m0; s[w * 2 + 1] = m1; }
    __syncthreads();
    if (threadIdx.x == 0) {
        for (int j = 1; j < 4; ++j) { m0 = fmaxf(m0, s[j * 2]); m1 = fmaxf(m1, s[j * 2 + 1]); }
        gstat[0] = m0; gstat[1] = m1;
    }
}

__global__ __launch_bounds__(256) void sum_partial_k(
    const float* __restrict__ ls, const unsigned* __restrict__ cntc,
    const float* __restrict__ gstat, float* __restrict__ part)
{
    float g0 = gstat[0], g1 = gstat[1];
    float s0 = 0.f, s1 = 0.f;
    for (int i = blockIdx.x * 256 + threadIdx.x; i < NN; i += 256 * 256) {
        unsigned c = cntc[i];
        if (c) {
            float fc = (float)c;
            s0 = fmaf(fc, __expf(ls[2 * i] - g0), s0);
            s1 = fmaf(fc, __expf(ls[2 * i + 1] - g1), s1);
        }
    }
#pragma unroll
    for (int d = 32; d; d >>= 1) {
        s0 += __shfl_xor(s0, d, 64);
        s1 += __shfl_xor(s1, d, 64);
    }
    __shared__ float s[8];
    int w = threadIdx.x >> 6;
    if ((threadIdx.x & 63) == 0) { s[w * 2] = s0; s[w * 2 + 1] = s1; }
    __syncthreads();
    if (threadIdx.x == 0) {
        for (int j = 1; j < 4; ++j) { s0 += s[j * 2]; s1 += s[j * 2 + 1]; }
        part[blockIdx.x * 2] = s0; part[blockIdx.x * 2 + 1] = s1;
    }
}

__global__ __launch_bounds__(256) void sum_final_k(const float* __restrict__ part,
                                                   float* __restrict__ gstat)
{
    float s0 = part[threadIdx.x * 2], s1 = part[threadIdx.x * 2 + 1];
#pragma unroll
    for (int d = 32; d; d >>= 1) {
        s0 += __shfl_xor(s0, d, 64);
        s1 += __shfl_xor(s1, d, 64);
    }
    __shared__ float s[8];
    int w = threadIdx.x >> 6;
    if ((threadIdx.x & 63) == 0) { s[w * 2] = s0; s[w * 2 + 1] = s1; }
    __syncthreads();
    if (threadIdx.x == 0) {
        for (int j = 1; j < 4; ++j) { s0 += s[j * 2]; s1 += s[j * 2 + 1]; }
        gstat[2] = 1.f / s0; gstat[3] = 1.f / s1;
    }
}

// ---------------------------------------------------------------------------
// Kernel 5: scale xh in place:  w[n,c] = xh[n,c] * exp(ls[n,h]-max_h)/denom_h
// ---------------------------------------------------------------------------
__global__ __launch_bounds__(256) void scale_k(
    float* __restrict__ xh, const float* __restrict__ ls,
    const float* __restrict__ gstat)
{
    int i = blockIdx.x * 256 + threadIdx.x;
    if (i >= NN * HC) return;
    int n = i >> 6, h = (i >> 5) & 1;
    float a = __expf(ls[n * 2 + h] - gstat[h]) * gstat[2 + h];
    xh[i] *= a;
}

// ---------------------------------------------------------------------------
// Kernel 6: single-block exclusive scan of cnt_row -> offs, cursor
// ---------------------------------------------------------------------------
__global__ __launch_bounds__(256) void scan_k(
    const unsigned* __restrict__ cnt, unsigned* __restrict__ offs,
    unsigned* __restrict__ cursor)
{
    __shared__ unsigned wtot[4];
    __shared__ unsigned carry_sh;
    int tid = threadIdx.x;
    int lane = tid & 63, wid = tid >> 6;
    if (tid == 0) carry_sh = 0;
    __syncthreads();
    for (int base = 0; base < NN; base += 256) {
        unsigned v = (base + tid < NN) ? cnt[base + tid] : 0u;
        unsigned orig = v;
#pragma unroll
        for (int d = 1; d < 64; d <<= 1) {
            unsigned t = __shfl_up(v, d, 64);
            if (lane >= d) v += t;
        }
        __syncthreads();                    // protect wtot from prev readers
        if (lane == 63) wtot[wid] = v;
        __syncthreads();
        unsigned wpre = 0;
        for (int j = 0; j < wid; ++j) wpre += wtot[j];
        unsigned carry = carry_sh;
        unsigned excl = carry + wpre + v - orig;
        if (base + tid < NN) { offs[base + tid] = excl; cursor[base + tid] = excl; }
        __syncthreads();
        if (tid == 0) carry_sh = carry + wtot[0] + wtot[1] + wtot[2] + wtot[3];
    }
}

// ---------------------------------------------------------------------------
// Kernel 7: scatter col values into row-CSR slots
// ---------------------------------------------------------------------------
__global__ __launch_bounds__(256) void scatter_k(
    const int* __restrict__ eidx, unsigned* __restrict__ cursor,
    unsigned* __restrict__ csr)
{
    int e = blockIdx.x * 256 + threadIdx.x;
    if (e < EE) {
        int r = eidx[e];
        int c = eidx[EE + e];
        unsigned slot = atomicAdd(&cursor[r], 1u);
        csr[slot] = (unsigned)c;
    }
}

// ---------------------------------------------------------------------------
// Kernel 8: gather-aggregate. One wave per node; lane = channel.
//   out[r, lane] = bias[lane] + sum over CSR neighbors of w[col*64 + lane]
// ---------------------------------------------------------------------------
__global__ __launch_bounds__(256) void aggregate_k(
    const float* __restrict__ w, const unsigned* __restrict__ csr,
    const unsigned* __restrict__ offs, const unsigned* __restrict__ cnt_row,
    const float* __restrict__ bias, float* __restrict__ out)
{
    int r = blockIdx.x * 4 + (threadIdx.x >> 6);
    int lane = threadIdx.x & 63;
    if (r >= NN) return;
    unsigned st = offs[r], deg = cnt_row[r];
    float acc = 0.f;
    unsigned j = 0;
    for (; j + 4 <= deg; j += 4) {
        unsigned c0 = csr[st + j], c1 = csr[st + j + 1];
        unsigned c2 = csr[st + j + 2], c3 = csr[st + j + 3];
        acc += w[(long)c0 * 64 + lane];
        acc += w[(long)c1 * 64 + lane];
        acc += w[(long)c2 * 64 + lane];
        acc += w[(long)c3 * 64 + lane];
    }
    for (; j < deg; ++j) acc += w[(long)csr[st + j] * 64 + lane];
    out[(long)r * 64 + lane] = acc + bias[lane];
}

// ---------------------------------------------------------------------------
extern "C" void kernel_launch(void* const* d_in, const int* in_sizes, int n_in,
                              void* d_out, int out_size, void* d_ws, size_t ws_size,
                              hipStream_t stream)
{
    const float* x    = (const float*)d_in[0];
    const int*   eidx = (const int*)d_in[1];   // harness contract: integer -> const int*
    const float* topo = (const float*)d_in[2];
    const float* Wl   = (const float*)d_in[3];
    const float* bl   = (const float*)d_in[4];
    const float* Wt   = (const float*)d_in[5];
    const float* bt   = (const float*)d_in[6];
    const float* attn = (const float*)d_in[7];
    const float* attt = (const float*)d_in[8];
    const float* bias = (const float*)d_in[9];
    float* out = (float*)d_out;

    char* p = (char*)d_ws;
    auto alloc = [&](size_t bytes) {
        char* r = p;
        p += (bytes + 511) & ~size_t(511);
        return r;
    };
    float*    xh      = (float*)   alloc((size_t)NN * HC * sizeof(float)); // 12.8 MB
    float*    ls      = (float*)   alloc((size_t)NN * 2 * sizeof(float));
    unsigned* cnt_row = (unsigned*)alloc((size_t)NN * sizeof(unsigned));
    unsigned* cnt_col = (unsigned*)alloc((size_t)NN * sizeof(unsigned));
    unsigned* offs    = (unsigned*)alloc((size_t)NN * sizeof(unsigned));
    unsigned* cursor  = (unsigned*)alloc((size_t)NN * sizeof(unsigned));
    unsigned* csr     = (unsigned*)alloc((size_t)EE * sizeof(unsigned));   // 3.2 MB
    float*    part    = (float*)   alloc(256 * 2 * sizeof(float));
    float*    gstat   = (float*)   alloc(4 * sizeof(float));

    hipMemsetAsync(cnt_row, 0, (size_t)NN * sizeof(unsigned), stream);
    hipMemsetAsync(cnt_col, 0, (size_t)NN * sizeof(unsigned), stream);

    node_stage_k<<<(NN * HC) / 256, 256, 0, stream>>>(x, topo, Wl, bl, Wt, bt,
                                                      attn, attt, xh, ls);
    count_k<<<(EE + 255) / 256, 256, 0, stream>>>(eidx, cnt_row, cnt_col);
    max_partial_k<<<256, 256, 0, stream>>>(ls, cnt_col, part);
    max_final_k<<<1, 256, 0, stream>>>(part, gstat);
    sum_partial_k<<<256, 256, 0, stream>>>(ls, cnt_col, gstat, part);
    sum_final_k<<<1, 256, 0, stream>>>(part, gstat);
    scale_k<<<(NN * HC) / 256, 256, 0, stream>>>(xh, ls, gstat);
    scan_k<<<1, 256, 0, stream>>>(cnt_row, offs, cursor);
    scatter_k<<<(EE + 255) / 256, 256, 0, stream>>>(eidx, cursor, csr);
    aggregate_k<<<(NN + 3) / 4, 256, 0, stream>>>(xh, csr, offs, cnt_row, bias, out);

    // Output 1: topology_features passthrough
    hipMemcpyAsync(out + (size_t)NN * HC, topo, (size_t)NN * 64 * sizeof(float),
                   hipMemcpyDeviceToDevice, stream);
}

// Round 2
// 289.081 us; speedup vs baseline: 1.5029x; 1.5029x over previous
//
#include <hip/hip_runtime.h>

#define NN 50000
#define EE 800000
#define HC 64
#define SCAN_BLOCKS 196   // 196*256 = 50176 >= NN

// ---------------------------------------------------------------------------
// Kernel 1: per-node linear layers + attention score.
// Block = 256 threads = 4 waves; each wave = 64 channels x 4 nodes (weight
// reuse x4). Weights staged in LDS as float4 with row stride 33 (superbank
// stride 1 -> minimal aliasing for ds_read_b128).
//   xh[n,c] = b_lin[c]  + sum_k x[n,k]   * W_lin[c,k]   (k<128)
//   th      = b_topo[c] + sum_k topo[n,k]* W_topo[c,k]  (k<64)
//   ls[n,h] = lrelu( sum_c xh*att_node + th*att_topo )  (no max needed; |s|<~3)
// ---------------------------------------------------------------------------
__global__ __launch_bounds__(256) void node_stage_k(
    const float* __restrict__ x, const float* __restrict__ topo,
    const float* __restrict__ Wl, const float* __restrict__ bl,
    const float* __restrict__ Wt, const float* __restrict__ bt,
    const float* __restrict__ attn, const float* __restrict__ attt,
    float* __restrict__ xh, float* __restrict__ ls)
{
    __shared__ float4 WL4[64][33];   // 33.0 KB
    __shared__ float4 WT4[64][17];   // 17.0 KB
    int tid = threadIdx.x;
    const float4* Wl4 = (const float4*)Wl;
    const float4* Wt4 = (const float4*)Wt;
    for (int i = tid; i < 64 * 32; i += 256) WL4[i >> 5][i & 31] = Wl4[i];
    for (int i = tid; i < 64 * 16; i += 256) WT4[i >> 4][i & 15] = Wt4[i];
    __syncthreads();

    int wid = tid >> 6, cl = tid & 63;
    int n0 = (blockIdx.x * 4 + wid) * 4;          // 3125 blocks * 16 nodes = 50000
    if (n0 >= NN) return;

    const float4* xp = (const float4*)(x + (size_t)n0 * 128);
    float b = bl[cl];
    float a0 = b, a1 = b, a2 = b, a3 = b;
#pragma unroll
    for (int k = 0; k < 32; ++k) {
        float4 w  = WL4[cl][k];
        float4 v0 = xp[k], v1 = xp[32 + k], v2 = xp[64 + k], v3 = xp[96 + k];
        a0 = fmaf(w.w, v0.w, fmaf(w.z, v0.z, fmaf(w.y, v0.y, fmaf(w.x, v0.x, a0))));
        a1 = fmaf(w.w, v1.w, fmaf(w.z, v1.z, fmaf(w.y, v1.y, fmaf(w.x, v1.x, a1))));
        a2 = fmaf(w.w, v2.w, fmaf(w.z, v2.z, fmaf(w.y, v2.y, fmaf(w.x, v2.x, a2))));
        a3 = fmaf(w.w, v3.w, fmaf(w.z, v3.z, fmaf(w.y, v3.y, fmaf(w.x, v3.x, a3))));
    }

    const float4* tp = (const float4*)(topo + (size_t)n0 * 64);
    float bt0 = bt[cl];
    float t0 = bt0, t1 = bt0, t2 = bt0, t3 = bt0;
#pragma unroll
    for (int k = 0; k < 16; ++k) {
        float4 w  = WT4[cl][k];
        float4 v0 = tp[k], v1 = tp[16 + k], v2 = tp[32 + k], v3 = tp[48 + k];
        t0 = fmaf(w.w, v0.w, fmaf(w.z, v0.z, fmaf(w.y, v0.y, fmaf(w.x, v0.x, t0))));
        t1 = fmaf(w.w, v1.w, fmaf(w.z, v1.z, fmaf(w.y, v1.y, fmaf(w.x, v1.x, t1))));
        t2 = fmaf(w.w, v2.w, fmaf(w.z, v2.z, fmaf(w.y, v2.y, fmaf(w.x, v2.x, t2))));
        t3 = fmaf(w.w, v3.w, fmaf(w.z, v3.z, fmaf(w.y, v3.y, fmaf(w.x, v3.x, t3))));
    }

    size_t ob = (size_t)n0 * 64 + cl;
    xh[ob] = a0; xh[ob + 64] = a1; xh[ob + 128] = a2; xh[ob + 192] = a3;

    float an = attn[cl], at = attt[cl];
    float s0 = a0 * an + t0 * at;
    float s1 = a1 * an + t1 * at;
    float s2 = a2 * an + t2 * at;
    float s3 = a3 * an + t3 * at;
#pragma unroll
    for (int d = 16; d >= 1; d >>= 1) {      // reduce within each 32-lane half
        s0 += __shfl_xor(s0, d, 64);
        s1 += __shfl_xor(s1, d, 64);
        s2 += __shfl_xor(s2, d, 64);
        s3 += __shfl_xor(s3, d, 64);
    }
    if ((cl & 31) == 0) {
        int h = cl >> 5;
        ls[(n0 + 0) * 2 + h] = s0 > 0.f ? s0 : 0.2f * s0;
        ls[(n0 + 1) * 2 + h] = s1 > 0.f ? s1 : 0.2f * s1;
        ls[(n0 + 2) * 2 + h] = s2 > 0.f ? s2 : 0.2f * s2;
        ls[(n0 + 3) * 2 + h] = s3 > 0.f ? s3 : 0.2f * s3;
    }
}

// ---------------------------------------------------------------------------
// Kernel 2: degree histograms (row for CSR, col for softmax weighting)
// ---------------------------------------------------------------------------
__global__ __launch_bounds__(256) void count_k(
    const int* __restrict__ eidx,
    unsigned* __restrict__ cnt_row, unsigned* __restrict__ cnt_col)
{
    int e = blockIdx.x * 256 + threadIdx.x;
    if (e < EE) {
        atomicAdd(&cnt_row[eidx[e]], 1u);
        atomicAdd(&cnt_col[eidx[EE + e]], 1u);
    }
}

// ---------------------------------------------------------------------------
// Softmax denominator (no max subtraction; |s| <= ~3 so exp is safe in fp32):
//   denom_h = sum over n of cnt_col[n] * exp(ls[n,h])
// ---------------------------------------------------------------------------
__global__ __launch_bounds__(256) void sum_partial_k(
    const float* __restrict__ ls, const unsigned* __restrict__ cntc,
    float* __restrict__ part)
{
    int i = blockIdx.x * 256 + threadIdx.x;
    float s0 = 0.f, s1 = 0.f;
    if (i < NN) {
        unsigned c = cntc[i];
        if (c) {
            float fc = (float)c;
            s0 = fc * __expf(ls[2 * i]);
            s1 = fc * __expf(ls[2 * i + 1]);
        }
    }
#pragma unroll
    for (int d = 32; d; d >>= 1) {
        s0 += __shfl_xor(s0, d, 64);
        s1 += __shfl_xor(s1, d, 64);
    }
    __shared__ float sh[8];
    int w = threadIdx.x >> 6;
    if ((threadIdx.x & 63) == 0) { sh[w * 2] = s0; sh[w * 2 + 1] = s1; }
    __syncthreads();
    if (threadIdx.x == 0) {
        for (int j = 1; j < 4; ++j) { s0 += sh[j * 2]; s1 += sh[j * 2 + 1]; }
        part[blockIdx.x * 2] = s0; part[blockIdx.x * 2 + 1] = s1;
    }
}

__global__ __launch_bounds__(256) void sum_final_k(const float* __restrict__ part,
                                                   float* __restrict__ gstat)
{
    int tid = threadIdx.x;
    float s0 = 0.f, s1 = 0.f;
    if (tid < SCAN_BLOCKS) { s0 = part[tid * 2]; s1 = part[tid * 2 + 1]; }
#pragma unroll
    for (int d = 32; d; d >>= 1) {
        s0 += __shfl_xor(s0, d, 64);
        s1 += __shfl_xor(s1, d, 64);
    }
    __shared__ float sh[8];
    int w = tid >> 6;
    if ((tid & 63) == 0) { sh[w * 2] = s0; sh[w * 2 + 1] = s1; }
    __syncthreads();
    if (tid == 0) {
        for (int j = 1; j < 4; ++j) { s0 += sh[j * 2]; s1 += sh[j * 2 + 1]; }
        gstat[0] = 1.f / s0; gstat[1] = 1.f / s1;
    }
}

// ---------------------------------------------------------------------------
// Kernel 5: scale xh in place (float4): w[n,c] = xh[n,c]*exp(ls[n,h])/denom_h
// ---------------------------------------------------------------------------
__global__ __launch_bounds__(256) void scale_k(
    float* __restrict__ xh, const float* __restrict__ ls,
    const float* __restrict__ gstat)
{
    int i4 = blockIdx.x * 256 + threadIdx.x;       // float4 index
    if (i4 >= NN * 16) return;
    int n = i4 >> 4, h = (i4 >> 3) & 1;
    float a = __expf(ls[n * 2 + h]) * gstat[h];
    float4 v = ((float4*)xh)[i4];
    v.x *= a; v.y *= a; v.z *= a; v.w *= a;
    ((float4*)xh)[i4] = v;
}

// ---------------------------------------------------------------------------
// Two-pass multi-block exclusive scan of cnt_row -> offs, cursor
// ---------------------------------------------------------------------------
__global__ __launch_bounds__(256) void scan1_k(
    const unsigned* __restrict__ cnt, unsigned* __restrict__ offs,
    unsigned* __restrict__ bsum)
{
    int tid = threadIdx.x, lane = tid & 63, wid = tid >> 6;
    int i = blockIdx.x * 256 + tid;
    unsigned v = (i < NN) ? cnt[i] : 0u, orig = v;
#pragma unroll
    for (int d = 1; d < 64; d <<= 1) {
        unsigned t = __shfl_up(v, d, 64);
        if (lane >= d) v += t;
    }
    __shared__ unsigned wtot[4];
    if (lane == 63) wtot[wid] = v;
    __syncthreads();
    unsigned wpre = 0;
    for (int j = 0; j < wid; ++j) wpre += wtot[j];
    if (i < NN) offs[i] = wpre + v - orig;          // exclusive within block
    if (tid == 255) bsum[blockIdx.x] = wpre + v;    // block total
}

__global__ __launch_bounds__(256) void scan2_k(
    const unsigned* __restrict__ bsum, unsigned* __restrict__ offs,
    unsigned* __restrict__ cursor)
{
    int tid = threadIdx.x, lane = tid & 63, wid = tid >> 6;
    unsigned v = (tid < (int)blockIdx.x) ? bsum[tid] : 0u;  // SCAN_BLOCKS<=256
#pragma unroll
    for (int d = 32; d; d >>= 1) v += __shfl_xor(v, d, 64);
    __shared__ unsigned sp[4];
    if (lane == 0) sp[wid] = v;
    __syncthreads();
    unsigned pre = sp[0] + sp[1] + sp[2] + sp[3];
    int i = blockIdx.x * 256 + tid;
    if (i < NN) {
        unsigned o = offs[i] + pre;
        offs[i] = o;
        cursor[i] = o;
    }
}

// ---------------------------------------------------------------------------
// Kernel 7: scatter col values into row-CSR slots
// ---------------------------------------------------------------------------
__global__ __launch_bounds__(256) void scatter_k(
    const int* __restrict__ eidx, unsigned* __restrict__ cursor,
    unsigned* __restrict__ csr)
{
    int e = blockIdx.x * 256 + threadIdx.x;
    if (e < EE) {
        int r = eidx[e];
        int c = eidx[EE + e];
        unsigned slot = atomicAdd(&cursor[r], 1u);
        csr[slot] = (unsigned)c;
    }
}

// ---------------------------------------------------------------------------
// Kernel 8: gather-aggregate. One wave per node; lane = channel.
//   out[r, lane] = bias[lane] + sum over CSR neighbors of w[col*64 + lane]
// ---------------------------------------------------------------------------
__global__ __launch_bounds__(256) void aggregate_k(
    const float* __restrict__ w, const unsigned* __restrict__ csr,
    const unsigned* __restrict__ offs, const unsigned* __restrict__ cnt_row,
    const float* __restrict__ bias, float* __restrict__ out)
{
    int r = blockIdx.x * 4 + (threadIdx.x >> 6);
    int lane = threadIdx.x & 63;
    if (r >= NN) return;
    unsigned st = offs[r], deg = cnt_row[r];
    float acc = 0.f;
    unsigned j = 0;
    for (; j + 4 <= deg; j += 4) {
        unsigned c0 = csr[st + j], c1 = csr[st + j + 1];
        unsigned c2 = csr[st + j + 2], c3 = csr[st + j + 3];
        acc += w[(size_t)c0 * 64 + lane];
        acc += w[(size_t)c1 * 64 + lane];
        acc += w[(size_t)c2 * 64 + lane];
        acc += w[(size_t)c3 * 64 + lane];
    }
    for (; j < deg; ++j) acc += w[(size_t)csr[st + j] * 64 + lane];
    out[(size_t)r * 64 + lane] = acc + bias[lane];
}

// ---------------------------------------------------------------------------
extern "C" void kernel_launch(void* const* d_in, const int* in_sizes, int n_in,
                              void* d_out, int out_size, void* d_ws, size_t ws_size,
                              hipStream_t stream)
{
    const float* x    = (const float*)d_in[0];
    const int*   eidx = (const int*)d_in[1];
    const float* topo = (const float*)d_in[2];
    const float* Wl   = (const float*)d_in[3];
    const float* bl   = (const float*)d_in[4];
    const float* Wt   = (const float*)d_in[5];
    const float* bt   = (const float*)d_in[6];
    const float* attn = (const float*)d_in[7];
    const float* attt = (const float*)d_in[8];
    const float* bias = (const float*)d_in[9];
    float* out = (float*)d_out;

    char* p = (char*)d_ws;
    auto alloc = [&](size_t bytes) {
        char* r = p;
        p += (bytes + 511) & ~size_t(511);
        return r;
    };
    float*    xh      = (float*)   alloc((size_t)NN * HC * sizeof(float)); // 12.8 MB
    float*    ls      = (float*)   alloc((size_t)NN * 2 * sizeof(float));
    unsigned* cnt_row = (unsigned*)alloc((size_t)NN * sizeof(unsigned));
    unsigned* cnt_col = (unsigned*)alloc((size_t)NN * sizeof(unsigned));
    unsigned* offs    = (unsigned*)alloc((size_t)NN * sizeof(unsigned));
    unsigned* cursor  = (unsigned*)alloc((size_t)NN * sizeof(unsigned));
    unsigned* csr     = (unsigned*)alloc((size_t)EE * sizeof(unsigned));   // 3.2 MB
    float*    part    = (float*)   alloc(256 * 2 * sizeof(float));
    float*    gstat   = (float*)   alloc(4 * sizeof(float));
    unsigned* bsum    = (unsigned*)alloc(256 * sizeof(unsigned));

    // one memset covering cnt_row..cnt_col (contiguous in ws)
    size_t zspan = (size_t)((char*)cnt_col - (char*)cnt_row) + (size_t)NN * sizeof(unsigned);
    hipMemsetAsync(cnt_row, 0, zspan, stream);

    node_stage_k<<<NN / 16, 256, 0, stream>>>(x, topo, Wl, bl, Wt, bt,
                                              attn, attt, xh, ls);
    count_k<<<(EE + 255) / 256, 256, 0, stream>>>(eidx, cnt_row, cnt_col);
    sum_partial_k<<<SCAN_BLOCKS, 256, 0, stream>>>(ls, cnt_col, part);
    sum_final_k<<<1, 256, 0, stream>>>(part, gstat);
    scale_k<<<(NN * 16 + 255) / 256, 256, 0, stream>>>(xh, ls, gstat);
    scan1_k<<<SCAN_BLOCKS, 256, 0, stream>>>(cnt_row, offs, bsum);
    scan2_k<<<SCAN_BLOCKS, 256, 0, stream>>>(bsum, offs, cursor);
    scatter_k<<<(EE + 255) / 256, 256, 0, stream>>>(eidx, cursor, csr);
    aggregate_k<<<(NN + 3) / 4, 256, 0, stream>>>(xh, csr, offs, cnt_row, bias, out);

    // Output 1: topology_features passthrough
    hipMemcpyAsync(out + (size_t)NN * HC, topo, (size_t)NN * 64 * sizeof(float),
                   hipMemcpyDeviceToDevice, stream);
}

// Round 4
// 242.108 us; speedup vs baseline: 1.7944x; 1.1940x over previous
//
#include <hip/hip_runtime.h>

#define NN 50000
#define EE 800000
#define HC 64
#define SCAN_BLOCKS 196   // 196*256 = 50176 >= NN

__device__ __forceinline__ float dot4(float4 a, float4 b) {
    return fmaf(a.w, b.w, fmaf(a.z, b.z, fmaf(a.y, b.y, a.x * b.x)));
}
__device__ __forceinline__ void fma4(float& acc, float4 a, float4 b) {
    acc = fmaf(a.x, b.x, fmaf(a.y, b.y, fmaf(a.z, b.z, fmaf(a.w, b.w, acc))));
}

// ---------------------------------------------------------------------------
// Precompute fused attention vectors (tiny, 1 block):
//   v_lin[h][k]  = sum_c att_node[h,c] * W_lin[h*32+c][k]    (2x128)
//   v_topo[h][k] = sum_c att_topo[h,c] * W_topo[h*32+c][k]   (2x64)
//   cst[h]       = sum_c att_node*b_lin + att_topo*b_topo
// fused layout: [0..255]=v_lin, [256..383]=v_topo, [384..385]=cst
// ---------------------------------------------------------------------------
__global__ __launch_bounds__(256) void precompute_k(
    const float* __restrict__ Wl, const float* __restrict__ bl,
    const float* __restrict__ Wt, const float* __restrict__ bt,
    const float* __restrict__ attn, const float* __restrict__ attt,
    float* __restrict__ fused)
{
    int tid = threadIdx.x;
    {
        int h = tid >> 7, k = tid & 127;
        float s = 0.f;
        for (int c = 0; c < 32; ++c)
            s = fmaf(attn[h * 32 + c], Wl[(h * 32 + c) * 128 + k], s);
        fused[h * 128 + k] = s;
    }
    if (tid < 128) {
        int h = tid >> 6, k = tid & 63;
        float s = 0.f;
        for (int c = 0; c < 32; ++c)
            s = fmaf(attt[h * 32 + c], Wt[(h * 32 + c) * 64 + k], s);
        fused[256 + h * 64 + k] = s;
    }
    if (tid < 2) {
        float s = 0.f;
        for (int c = 0; c < 32; ++c)
            s += attn[tid * 32 + c] * bl[tid * 32 + c]
               + attt[tid * 32 + c] * bt[tid * 32 + c];
        fused[384 + tid] = s;
    }
}

// ---------------------------------------------------------------------------
// score_k: s[n,h] = lrelu( v_lin[h].x[n] + v_topo[h].topo[n] + cst[h] )
// Fully coalesced: per quad of nodes, wave reads 2x 1KB segments of x
// (lane l -> row n0+(l>>5), float4 k=(l&31)) and 1x 1KB of topo (4 rows).
// Also emits the topo passthrough (free - topo is already streaming through).
// ---------------------------------------------------------------------------
__global__ __launch_bounds__(256) void score_k(
    const float* __restrict__ x, const float* __restrict__ topo,
    const float* __restrict__ fused, float* __restrict__ ls,
    float* __restrict__ topo_out)
{
    const float4* x4  = (const float4*)x;
    const float4* t4  = (const float4*)topo;
    const float4* vl4 = (const float4*)fused;          // [2][32]
    const float4* vt4 = (const float4*)(fused + 256);  // [2][16]
    float4* to4 = (float4*)topo_out;
    int tid = threadIdx.x, l = tid & 63;
    float4 vA0 = vl4[l & 31], vA1 = vl4[32 + (l & 31)];
    float4 vT0 = vt4[l & 15], vT1 = vt4[16 + (l & 15)];
    float c0 = fused[384], c1 = fused[385];
    int w = blockIdx.x * 4 + (tid >> 6);   // wave id; 16 nodes per wave
#pragma unroll
    for (int q = 0; q < 4; ++q) {
        int n0 = w * 16 + q * 4;
        if (n0 >= NN) return;
        float4 A1 = x4[n0 * 32 + l];         // rows n0, n0+1
        float4 A2 = x4[(n0 + 2) * 32 + l];   // rows n0+2, n0+3
        float4 B  = t4[n0 * 16 + l];         // rows n0..n0+3
        to4[n0 * 16 + l] = B;                // passthrough output 1
        float p10 = dot4(A1, vA0), p11 = dot4(A1, vA1);
        float p20 = dot4(A2, vA0), p21 = dot4(A2, vA1);
        float q0  = dot4(B,  vT0), q1  = dot4(B,  vT1);
#pragma unroll
        for (int d = 16; d >= 1; d >>= 1) {   // reduce within 32-lane halves
            p10 += __shfl_xor(p10, d, 64); p11 += __shfl_xor(p11, d, 64);
            p20 += __shfl_xor(p20, d, 64); p21 += __shfl_xor(p21, d, 64);
        }
#pragma unroll
        for (int d = 8; d >= 1; d >>= 1) {    // reduce within 16-lane groups
            q0 += __shfl_xor(q0, d, 64); q1 += __shfl_xor(q1, d, 64);
        }
        float x00=__shfl(p10,0), x10=__shfl(p10,32), x20=__shfl(p20,0), x30=__shfl(p20,32);
        float x01=__shfl(p11,0), x11=__shfl(p11,32), x21=__shfl(p21,0), x31=__shfl(p21,32);
        float q00=__shfl(q0,0),  q10=__shfl(q0,16),  q20=__shfl(q0,32), q30=__shfl(q0,48);
        float q01=__shfl(q1,0),  q11=__shfl(q1,16),  q21=__shfl(q1,32), q31=__shfl(q1,48);
        if (l < 8) {
            int j = l >> 1, h = l & 1;
            float xs, qs, cs;
            if (h) { xs = j==0?x01:j==1?x11:j==2?x21:x31;
                     qs = j==0?q01:j==1?q11:j==2?q21:q31; cs = c1; }
            else   { xs = j==0?x00:j==1?x10:j==2?x20:x30;
                     qs = j==0?q00:j==1?q10:j==2?q20:q30; cs = c0; }
            float s = xs + qs + cs;
            ls[(n0 + j) * 2 + h] = s > 0.f ? s : 0.2f * s;
        }
    }
}

// ---------------------------------------------------------------------------
// gemm_scale_k: w[n,c] = (x[n]·W_lin[c] + b_lin[c]) * exp(ls[n,h])/denom_h
// Wave = 64 channels x 8 nodes (weight reuse x8). Weights in LDS, row
// stride 132 floats (528B: 16B-aligned, near-ideal b128 banking).
// ---------------------------------------------------------------------------
__global__ __launch_bounds__(256) void gemm_scale_k(
    const float* __restrict__ x, const float* __restrict__ Wl,
    const float* __restrict__ bl, const float* __restrict__ ls,
    const float* __restrict__ gstat, float* __restrict__ wout)
{
    __shared__ float WLs[64 * 132];   // 33.8 KB -> 4 blocks/CU
    int tid = threadIdx.x;
    const float4* Wl4 = (const float4*)Wl;
    for (int i = tid; i < 2048; i += 256) {
        float4 v = Wl4[i];
        *(float4*)&WLs[(i >> 5) * 132 + ((i & 31) << 2)] = v;
    }
    __syncthreads();

    int cl = tid & 63;
    int n0 = (blockIdx.x * 4 + (tid >> 6)) * 8;
    if (n0 >= NN) return;                 // NN%8==0: waves fully valid or not
    const float4* xp = (const float4*)(x + (size_t)n0 * 128);
    float b = bl[cl];
    float a0=b,a1=b,a2=b,a3=b,a4=b,a5=b,a6=b,a7=b;
#pragma unroll 2
    for (int k4 = 0; k4 < 32; ++k4) {
        float4 wf = *(const float4*)&WLs[cl * 132 + (k4 << 2)];
        float4 v0 = xp[k4],        v1 = xp[32 + k4];
        float4 v2 = xp[64 + k4],   v3 = xp[96 + k4];
        float4 v4 = xp[128 + k4],  v5 = xp[160 + k4];
        float4 v6 = xp[192 + k4],  v7 = xp[224 + k4];
        fma4(a0, wf, v0); fma4(a1, wf, v1); fma4(a2, wf, v2); fma4(a3, wf, v3);
        fma4(a4, wf, v4); fma4(a5, wf, v5); fma4(a6, wf, v6); fma4(a7, wf, v7);
    }
    int h = cl >> 5;
    float gi = gstat[h];
    size_t ob = (size_t)n0 * 64 + cl;
    wout[ob      ] = a0 * (__expf(ls[(n0+0)*2+h]) * gi);
    wout[ob +  64] = a1 * (__expf(ls[(n0+1)*2+h]) * gi);
    wout[ob + 128] = a2 * (__expf(ls[(n0+2)*2+h]) * gi);
    wout[ob + 192] = a3 * (__expf(ls[(n0+3)*2+h]) * gi);
    wout[ob + 256] = a4 * (__expf(ls[(n0+4)*2+h]) * gi);
    wout[ob + 320] = a5 * (__expf(ls[(n0+5)*2+h]) * gi);
    wout[ob + 384] = a6 * (__expf(ls[(n0+6)*2+h]) * gi);
    wout[ob + 448] = a7 * (__expf(ls[(n0+7)*2+h]) * gi);
}

// ---------------------------------------------------------------------------
// Degree histograms
// ---------------------------------------------------------------------------
__global__ __launch_bounds__(256) void count_k(
    const int* __restrict__ eidx,
    unsigned* __restrict__ cnt_row, unsigned* __restrict__ cnt_col)
{
    int e = blockIdx.x * 256 + threadIdx.x;
    if (e < EE) {
        atomicAdd(&cnt_row[eidx[e]], 1u);
        atomicAdd(&cnt_col[eidx[EE + e]], 1u);
    }
}

// ---------------------------------------------------------------------------
// Softmax denominator: denom_h = sum_n cnt_col[n]*exp(ls[n,h])  (|s|<~4, safe)
// ---------------------------------------------------------------------------
__global__ __launch_bounds__(256) void sum_partial_k(
    const float* __restrict__ ls, const unsigned* __restrict__ cntc,
    float* __restrict__ part)
{
    int i = blockIdx.x * 256 + threadIdx.x;
    float s0 = 0.f, s1 = 0.f;
    if (i < NN) {
        unsigned c = cntc[i];
        if (c) {
            float fc = (float)c;
            s0 = fc * __expf(ls[2 * i]);
            s1 = fc * __expf(ls[2 * i + 1]);
        }
    }
#pragma unroll
    for (int d = 32; d; d >>= 1) {
        s0 += __shfl_xor(s0, d, 64);
        s1 += __shfl_xor(s1, d, 64);
    }
    __shared__ float sh[8];
    int w = threadIdx.x >> 6;
    if ((threadIdx.x & 63) == 0) { sh[w * 2] = s0; sh[w * 2 + 1] = s1; }
    __syncthreads();
    if (threadIdx.x == 0) {
        for (int j = 1; j < 4; ++j) { s0 += sh[j * 2]; s1 += sh[j * 2 + 1]; }
        part[blockIdx.x * 2] = s0; part[blockIdx.x * 2 + 1] = s1;
    }
}

__global__ __launch_bounds__(256) void sum_final_k(const float* __restrict__ part,
                                                   float* __restrict__ gstat)
{
    int tid = threadIdx.x;
    float s0 = 0.f, s1 = 0.f;
    if (tid < SCAN_BLOCKS) { s0 = part[tid * 2]; s1 = part[tid * 2 + 1]; }
#pragma unroll
    for (int d = 32; d; d >>= 1) {
        s0 += __shfl_xor(s0, d, 64);
        s1 += __shfl_xor(s1, d, 64);
    }
    __shared__ float sh[8];
    int w = tid >> 6;
    if ((tid & 63) == 0) { sh[w * 2] = s0; sh[w * 2 + 1] = s1; }
    __syncthreads();
    if (tid == 0) {
        for (int j = 1; j < 4; ++j) { s0 += sh[j * 2]; s1 += sh[j * 2 + 1]; }
        gstat[0] = 1.f / s0; gstat[1] = 1.f / s1;
    }
}

// ---------------------------------------------------------------------------
// Two-pass multi-block exclusive scan of cnt_row -> offs, cursor
// ---------------------------------------------------------------------------
__global__ __launch_bounds__(256) void scan1_k(
    const unsigned* __restrict__ cnt, unsigned* __restrict__ offs,
    unsigned* __restrict__ bsum)
{
    int tid = threadIdx.x, lane = tid & 63, wid = tid >> 6;
    int i = blockIdx.x * 256 + tid;
    unsigned v = (i < NN) ? cnt[i] : 0u, orig = v;
#pragma unroll
    for (int d = 1; d < 64; d <<= 1) {
        unsigned t = __shfl_up(v, d, 64);
        if (lane >= d) v += t;
    }
    __shared__ unsigned wtot[4];
    if (lane == 63) wtot[wid] = v;
    __syncthreads();
    unsigned wpre = 0;
    for (int j = 0; j < wid; ++j) wpre += wtot[j];
    if (i < NN) offs[i] = wpre + v - orig;
    if (tid == 255) bsum[blockIdx.x] = wpre + v;
}

__global__ __launch_bounds__(256) void scan2_k(
    const unsigned* __restrict__ bsum, unsigned* __restrict__ offs,
    unsigned* __restrict__ cursor)
{
    int tid = threadIdx.x, lane = tid & 63, wid = tid >> 6;
    unsigned v = (tid < (int)blockIdx.x) ? bsum[tid] : 0u;
#pragma unroll
    for (int d = 32; d; d >>= 1) v += __shfl_xor(v, d, 64);
    __shared__ unsigned sp[4];
    if (lane == 0) sp[wid] = v;
    __syncthreads();
    unsigned pre = sp[0] + sp[1] + sp[2] + sp[3];
    int i = blockIdx.x * 256 + tid;
    if (i < NN) {
        unsigned o = offs[i] + pre;
        offs[i] = o;
        cursor[i] = o;
    }
}

// ---------------------------------------------------------------------------
// Scatter col into row-CSR slots
// ---------------------------------------------------------------------------
__global__ __launch_bounds__(256) void scatter_k(
    const int* __restrict__ eidx, unsigned* __restrict__ cursor,
    unsigned* __restrict__ csr)
{
    int e = blockIdx.x * 256 + threadIdx.x;
    if (e < EE) {
        int r = eidx[e];
        int c = eidx[EE + e];
        unsigned slot = atomicAdd(&cursor[r], 1u);
        csr[slot] = (unsigned)c;
    }
}

// ---------------------------------------------------------------------------
// Gather-aggregate: out[r,lane] = bias[lane] + sum_{CSR} w[col*64+lane]
// ---------------------------------------------------------------------------
__global__ __launch_bounds__(256) void aggregate_k(
    const float* __restrict__ w, const unsigned* __restrict__ csr,
    const unsigned* __restrict__ offs, const unsigned* __restrict__ cnt_row,
    const float* __restrict__ bias, float* __restrict__ out)
{
    int r = blockIdx.x * 4 + (threadIdx.x >> 6);
    int lane = threadIdx.x & 63;
    if (r >= NN) return;
    unsigned st = offs[r], deg = cnt_row[r];
    float acc = 0.f;
    unsigned j = 0;
    for (; j + 4 <= deg; j += 4) {
        unsigned c0 = csr[st + j], c1 = csr[st + j + 1];
        unsigned c2 = csr[st + j + 2], c3 = csr[st + j + 3];
        acc += w[(size_t)c0 * 64 + lane];
        acc += w[(size_t)c1 * 64 + lane];
        acc += w[(size_t)c2 * 64 + lane];
        acc += w[(size_t)c3 * 64 + lane];
    }
    for (; j < deg; ++j) acc += w[(size_t)csr[st + j] * 64 + lane];
    out[(size_t)r * 64 + lane] = acc + bias[lane];
}

// ---------------------------------------------------------------------------
extern "C" void kernel_launch(void* const* d_in, const int* in_sizes, int n_in,
                              void* d_out, int out_size, void* d_ws, size_t ws_size,
                              hipStream_t stream)
{
    const float* x    = (const float*)d_in[0];
    const int*   eidx = (const int*)d_in[1];
    const float* topo = (const float*)d_in[2];
    const float* Wl   = (const float*)d_in[3];
    const float* bl   = (const float*)d_in[4];
    const float* Wt   = (const float*)d_in[5];
    const float* bt   = (const float*)d_in[6];
    const float* attn = (const float*)d_in[7];
    const float* attt = (const float*)d_in[8];
    const float* bias = (const float*)d_in[9];
    float* out = (float*)d_out;

    char* p = (char*)d_ws;
    auto alloc = [&](size_t bytes) {
        char* r = p;
        p += (bytes + 511) & ~size_t(511);
        return r;
    };
    float*    wbuf    = (float*)   alloc((size_t)NN * HC * sizeof(float)); // 12.8 MB
    float*    ls      = (float*)   alloc((size_t)NN * 2 * sizeof(float));
    unsigned* cnt_row = (unsigned*)alloc((size_t)NN * sizeof(unsigned));
    unsigned* cnt_col = (unsigned*)alloc((size_t)NN * sizeof(unsigned));
    unsigned* offs    = (unsigned*)alloc((size_t)NN * sizeof(unsigned));
    unsigned* cursor  = (unsigned*)alloc((size_t)NN * sizeof(unsigned));
    unsigned* csr     = (unsigned*)alloc((size_t)EE * sizeof(unsigned));   // 3.2 MB
    float*    part    = (float*)   alloc(256 * 2 * sizeof(float));
    float*    gstat   = (float*)   alloc(4 * sizeof(float));
    unsigned* bsum    = (unsigned*)alloc(256 * sizeof(unsigned));
    float*    fused   = (float*)   alloc(512 * sizeof(float));

    size_t zspan = (size_t)((char*)cnt_col - (char*)cnt_row) + (size_t)NN * sizeof(unsigned);
    (void)hipMemsetAsync(cnt_row, 0, zspan, stream);

    count_k<<<(EE + 255) / 256, 256, 0, stream>>>(eidx, cnt_row, cnt_col);
    precompute_k<<<1, 256, 0, stream>>>(Wl, bl, Wt, bt, attn, attt, fused);
    score_k<<<782, 256, 0, stream>>>(x, topo, fused, ls, out + (size_t)NN * HC);
    sum_partial_k<<<SCAN_BLOCKS, 256, 0, stream>>>(ls, cnt_col, part);
    sum_final_k<<<1, 256, 0, stream>>>(part, gstat);
    gemm_scale_k<<<(NN + 31) / 32, 256, 0, stream>>>(x, Wl, bl, ls, gstat, wbuf);
    scan1_k<<<SCAN_BLOCKS, 256, 0, stream>>>(cnt_row, offs, bsum);
    scan2_k<<<SCAN_BLOCKS, 256, 0, stream>>>(bsum, offs, cursor);
    scatter_k<<<(EE + 255) / 256, 256, 0, stream>>>(eidx, cursor, csr);
    aggregate_k<<<(NN + 3) / 4, 256, 0, stream>>>(wbuf, csr, offs, cnt_row, bias, out);
}

// Round 5
// 204.008 us; speedup vs baseline: 2.1296x; 1.1868x over previous
//
#include <hip/hip_runtime.h>

#define NN 50000
#define EE 800000
#define HC 64
#define SCAN_BLOCKS 196   // 196*256 = 50176 >= NN
#define NPAD 50176
#define HG 64             // histogram blocks; EE/HG = 12500 exact

__device__ __forceinline__ float dot4(float4 a, float4 b) {
    return fmaf(a.w, b.w, fmaf(a.z, b.z, fmaf(a.y, b.y, a.x * b.x)));
}
__device__ __forceinline__ void fma4(float& acc, float4 a, float4 b) {
    acc = fmaf(a.x, b.x, fmaf(a.y, b.y, fmaf(a.z, b.z, fmaf(a.w, b.w, acc))));
}

// ---------------------------------------------------------------------------
// Precompute fused attention vectors (tiny, 1 block):
//   v_lin[h][k]  = sum_c att_node[h,c] * W_lin[h*32+c][k]    (2x128)
//   v_topo[h][k] = sum_c att_topo[h,c] * W_topo[h*32+c][k]   (2x64)
//   cst[h]       = sum_c att_node*b_lin + att_topo*b_topo
// fused layout: [0..255]=v_lin, [256..383]=v_topo, [384..385]=cst
// ---------------------------------------------------------------------------
__global__ __launch_bounds__(256) void precompute_k(
    const float* __restrict__ Wl, const float* __restrict__ bl,
    const float* __restrict__ Wt, const float* __restrict__ bt,
    const float* __restrict__ attn, const float* __restrict__ attt,
    float* __restrict__ fused)
{
    int tid = threadIdx.x;
    {
        int h = tid >> 7, k = tid & 127;
        float s = 0.f;
        for (int c = 0; c < 32; ++c)
            s = fmaf(attn[h * 32 + c], Wl[(h * 32 + c) * 128 + k], s);
        fused[h * 128 + k] = s;
    }
    if (tid < 128) {
        int h = tid >> 6, k = tid & 63;
        float s = 0.f;
        for (int c = 0; c < 32; ++c)
            s = fmaf(attt[h * 32 + c], Wt[(h * 32 + c) * 64 + k], s);
        fused[256 + h * 64 + k] = s;
    }
    if (tid < 2) {
        float s = 0.f;
        for (int c = 0; c < 32; ++c)
            s += attn[tid * 32 + c] * bl[tid * 32 + c]
               + attt[tid * 32 + c] * bt[tid * 32 + c];
        fused[384 + tid] = s;
    }
}

// ---------------------------------------------------------------------------
// score_k: es[n,h] = exp(lrelu( v_lin[h].x[n] + v_topo[h].topo[n] + cst[h] ))
// Fully coalesced; also emits the topo passthrough (free - already streaming).
// ---------------------------------------------------------------------------
__global__ __launch_bounds__(256) void score_k(
    const float* __restrict__ x, const float* __restrict__ topo,
    const float* __restrict__ fused, float* __restrict__ es,
    float* __restrict__ topo_out)
{
    const float4* x4  = (const float4*)x;
    const float4* t4  = (const float4*)topo;
    const float4* vl4 = (const float4*)fused;          // [2][32]
    const float4* vt4 = (const float4*)(fused + 256);  // [2][16]
    float4* to4 = (float4*)topo_out;
    int tid = threadIdx.x, l = tid & 63;
    float4 vA0 = vl4[l & 31], vA1 = vl4[32 + (l & 31)];
    float4 vT0 = vt4[l & 15], vT1 = vt4[16 + (l & 15)];
    float c0 = fused[384], c1 = fused[385];
    int w = blockIdx.x * 4 + (tid >> 6);   // wave id; 16 nodes per wave
#pragma unroll
    for (int q = 0; q < 4; ++q) {
        int n0 = w * 16 + q * 4;
        if (n0 >= NN) return;
        float4 A1 = x4[n0 * 32 + l];         // rows n0, n0+1
        float4 A2 = x4[(n0 + 2) * 32 + l];   // rows n0+2, n0+3
        float4 B  = t4[n0 * 16 + l];         // rows n0..n0+3
        to4[n0 * 16 + l] = B;                // passthrough output 1
        float p10 = dot4(A1, vA0), p11 = dot4(A1, vA1);
        float p20 = dot4(A2, vA0), p21 = dot4(A2, vA1);
        float q0  = dot4(B,  vT0), q1  = dot4(B,  vT1);
#pragma unroll
        for (int d = 16; d >= 1; d >>= 1) {   // reduce within 32-lane halves
            p10 += __shfl_xor(p10, d, 64); p11 += __shfl_xor(p11, d, 64);
            p20 += __shfl_xor(p20, d, 64); p21 += __shfl_xor(p21, d, 64);
        }
#pragma unroll
        for (int d = 8; d >= 1; d >>= 1) {    // reduce within 16-lane groups
            q0 += __shfl_xor(q0, d, 64); q1 += __shfl_xor(q1, d, 64);
        }
        float x00=__shfl(p10,0), x10=__shfl(p10,32), x20=__shfl(p20,0), x30=__shfl(p20,32);
        float x01=__shfl(p11,0), x11=__shfl(p11,32), x21=__shfl(p21,0), x31=__shfl(p21,32);
        float q00=__shfl(q0,0),  q10=__shfl(q0,16),  q20=__shfl(q0,32), q30=__shfl(q0,48);
        float q01=__shfl(q1,0),  q11=__shfl(q1,16),  q21=__shfl(q1,32), q31=__shfl(q1,48);
        if (l < 8) {
            int j = l >> 1, h = l & 1;
            float xs, qs, cs;
            if (h) { xs = j==0?x01:j==1?x11:j==2?x21:x31;
                     qs = j==0?q01:j==1?q11:j==2?q21:q31; cs = c1; }
            else   { xs = j==0?x00:j==1?x10:j==2?x20:x30;
                     qs = j==0?q00:j==1?q10:j==2?q20:q30; cs = c0; }
            float s = xs + qs + cs;
            float lr = s > 0.f ? s : 0.2f * s;
            es[(n0 + j) * 2 + h] = __expf(lr);
        }
    }
}

// ---------------------------------------------------------------------------
// hist_sum_k: one edge pass, zero global atomics.
//  - row histogram privatized in LDS as packed 2xu16 per u32 (per-block
//    counts < 2^16 so no carry); slab written coalesced to part_hist[g].
//  - softmax denominator partials: s_h += es[col[e],h] (8B gathers from
//    the 400KB L2-resident es table).
// ---------------------------------------------------------------------------
__global__ __launch_bounds__(256) void hist_sum_k(
    const int* __restrict__ eidx, const float* __restrict__ es,
    unsigned* __restrict__ part_hist, float* __restrict__ part_sum)
{
    __shared__ unsigned h32[NPAD / 2];   // 100,352 B
    int tid = threadIdx.x, g = blockIdx.x;
    for (int i = tid; i < NPAD / 2; i += 256) h32[i] = 0u;
    __syncthreads();

    const float2* es2 = (const float2*)es;
    int e0 = g * (EE / HG);
    float s0 = 0.f, s1 = 0.f;
    for (int e = e0 + tid; e < e0 + EE / HG; e += 256) {
        int r = eidx[e];
        int c = eidx[EE + e];
        atomicAdd(&h32[r >> 1], 1u << ((r & 1) << 4));   // LDS ds_add
        float2 ev = es2[c];
        s0 += ev.x; s1 += ev.y;
    }
#pragma unroll
    for (int d = 32; d; d >>= 1) {
        s0 += __shfl_xor(s0, d, 64);
        s1 += __shfl_xor(s1, d, 64);
    }
    __shared__ float sh[8];
    if ((tid & 63) == 0) { sh[(tid >> 6) * 2] = s0; sh[(tid >> 6) * 2 + 1] = s1; }
    __syncthreads();                      // also fences all LDS atomics
    if (tid == 0) {
        for (int j = 1; j < 4; ++j) { s0 += sh[2 * j]; s1 += sh[2 * j + 1]; }
        part_sum[g * 2] = s0; part_sum[g * 2 + 1] = s1;
    }
    unsigned* dst = part_hist + (size_t)g * (NPAD / 2);
    for (int i = tid; i < NPAD / 2; i += 256) dst[i] = h32[i];
}

__global__ __launch_bounds__(64) void sum_final_k(const float* __restrict__ part,
                                                  float* __restrict__ gstat)
{
    int tid = threadIdx.x;                // one wave, HG=64 partials
    float s0 = part[tid * 2], s1 = part[tid * 2 + 1];
#pragma unroll
    for (int d = 32; d; d >>= 1) {
        s0 += __shfl_xor(s0, d, 64);
        s1 += __shfl_xor(s1, d, 64);
    }
    if (tid == 0) { gstat[0] = 1.f / s0; gstat[1] = 1.f / s1; }
}

// ---------------------------------------------------------------------------
// gemm_scale_k: w[n,c] = (x[n]·W_lin[c] + b_lin[c]) * es[n,h]/denom_h
// Wave = 64 channels x 8 nodes (weight reuse x8). Weights in LDS, row
// stride 132 floats (528B: 16B-aligned, near-ideal b128 banking).
// ---------------------------------------------------------------------------
__global__ __launch_bounds__(256) void gemm_scale_k(
    const float* __restrict__ x, const float* __restrict__ Wl,
    const float* __restrict__ bl, const float* __restrict__ es,
    const float* __restrict__ gstat, float* __restrict__ wout)
{
    __shared__ float WLs[64 * 132];   // 33.8 KB
    int tid = threadIdx.x;
    const float4* Wl4 = (const float4*)Wl;
    for (int i = tid; i < 2048; i += 256) {
        float4 v = Wl4[i];
        *(float4*)&WLs[(i >> 5) * 132 + ((i & 31) << 2)] = v;
    }
    __syncthreads();

    int cl = tid & 63;
    int n0 = (blockIdx.x * 4 + (tid >> 6)) * 8;
    if (n0 >= NN) return;
    const float4* xp = (const float4*)(x + (size_t)n0 * 128);
    float b = bl[cl];
    float a0=b,a1=b,a2=b,a3=b,a4=b,a5=b,a6=b,a7=b;
#pragma unroll 2
    for (int k4 = 0; k4 < 32; ++k4) {
        float4 wf = *(const float4*)&WLs[cl * 132 + (k4 << 2)];
        float4 v0 = xp[k4],        v1 = xp[32 + k4];
        float4 v2 = xp[64 + k4],   v3 = xp[96 + k4];
        float4 v4 = xp[128 + k4],  v5 = xp[160 + k4];
        float4 v6 = xp[192 + k4],  v7 = xp[224 + k4];
        fma4(a0, wf, v0); fma4(a1, wf, v1); fma4(a2, wf, v2); fma4(a3, wf, v3);
        fma4(a4, wf, v4); fma4(a5, wf, v5); fma4(a6, wf, v6); fma4(a7, wf, v7);
    }
    int h = cl >> 5;
    float gi = gstat[h];
    size_t ob = (size_t)n0 * 64 + cl;
    wout[ob      ] = a0 * (es[(n0+0)*2+h] * gi);
    wout[ob +  64] = a1 * (es[(n0+1)*2+h] * gi);
    wout[ob + 128] = a2 * (es[(n0+2)*2+h] * gi);
    wout[ob + 192] = a3 * (es[(n0+3)*2+h] * gi);
    wout[ob + 256] = a4 * (es[(n0+4)*2+h] * gi);
    wout[ob + 320] = a5 * (es[(n0+5)*2+h] * gi);
    wout[ob + 384] = a6 * (es[(n0+6)*2+h] * gi);
    wout[ob + 448] = a7 * (es[(n0+7)*2+h] * gi);
}

// ---------------------------------------------------------------------------
// scan1: fuse 64-way u16 partial-histogram reduction with block-local scan
// ---------------------------------------------------------------------------
__global__ __launch_bounds__(256) void scan1_k(
    const unsigned short* __restrict__ ph, unsigned* __restrict__ cnt_row,
    unsigned* __restrict__ offs, unsigned* __restrict__ bsum)
{
    int tid = threadIdx.x, lane = tid & 63, wid = tid >> 6;
    int i = blockIdx.x * 256 + tid;       // always < NPAD
    unsigned v = 0;
#pragma unroll 8
    for (int g = 0; g < HG; ++g) v += ph[(size_t)g * NPAD + i];
    if (i < NN) cnt_row[i] = v;
    unsigned orig = v;
#pragma unroll
    for (int d = 1; d < 64; d <<= 1) {
        unsigned t = __shfl_up(v, d, 64);
        if (lane >= d) v += t;
    }
    __shared__ unsigned wtot[4];
    if (lane == 63) wtot[wid] = v;
    __syncthreads();
    unsigned wpre = 0;
    for (int j = 0; j < wid; ++j) wpre += wtot[j];
    if (i < NN) offs[i] = wpre + v - orig;
    if (tid == 255) bsum[blockIdx.x] = wpre + v;
}

__global__ __launch_bounds__(256) void scan2_k(
    const unsigned* __restrict__ bsum, unsigned* __restrict__ offs,
    unsigned* __restrict__ cursor)
{
    int tid = threadIdx.x, lane = tid & 63, wid = tid >> 6;
    unsigned v = (tid < (int)blockIdx.x) ? bsum[tid] : 0u;
#pragma unroll
    for (int d = 32; d; d >>= 1) v += __shfl_xor(v, d, 64);
    __shared__ unsigned sp[4];
    if (lane == 0) sp[wid] = v;
    __syncthreads();
    unsigned pre = sp[0] + sp[1] + sp[2] + sp[3];
    int i = blockIdx.x * 256 + tid;
    if (i < NN) {
        unsigned o = offs[i] + pre;
        offs[i] = o;
        cursor[i] = o;
    }
}

// ---------------------------------------------------------------------------
// Scatter col into row-CSR slots
// ---------------------------------------------------------------------------
__global__ __launch_bounds__(256) void scatter_k(
    const int* __restrict__ eidx, unsigned* __restrict__ cursor,
    unsigned* __restrict__ csr)
{
    int e = blockIdx.x * 256 + threadIdx.x;
    if (e < EE) {
        int r = eidx[e];
        int c = eidx[EE + e];
        unsigned slot = atomicAdd(&cursor[r], 1u);
        csr[slot] = (unsigned)c;
    }
}

// ---------------------------------------------------------------------------
// Gather-aggregate: out[r,lane] = bias[lane] + sum_{CSR} w[col*64+lane]
// ---------------------------------------------------------------------------
__global__ __launch_bounds__(256) void aggregate_k(
    const float* __restrict__ w, const unsigned* __restrict__ csr,
    const unsigned* __restrict__ offs, const unsigned* __restrict__ cnt_row,
    const float* __restrict__ bias, float* __restrict__ out)
{
    int r = blockIdx.x * 4 + (threadIdx.x >> 6);
    int lane = threadIdx.x & 63;
    if (r >= NN) return;
    unsigned st = offs[r], deg = cnt_row[r];
    float acc = 0.f;
    unsigned j = 0;
    for (; j + 4 <= deg; j += 4) {
        unsigned c0 = csr[st + j], c1 = csr[st + j + 1];
        unsigned c2 = csr[st + j + 2], c3 = csr[st + j + 3];
        acc += w[(size_t)c0 * 64 + lane];
        acc += w[(size_t)c1 * 64 + lane];
        acc += w[(size_t)c2 * 64 + lane];
        acc += w[(size_t)c3 * 64 + lane];
    }
    for (; j < deg; ++j) acc += w[(size_t)csr[st + j] * 64 + lane];
    out[(size_t)r * 64 + lane] = acc + bias[lane];
}

// ---------------------------------------------------------------------------
extern "C" void kernel_launch(void* const* d_in, const int* in_sizes, int n_in,
                              void* d_out, int out_size, void* d_ws, size_t ws_size,
                              hipStream_t stream)
{
    const float* x    = (const float*)d_in[0];
    const int*   eidx = (const int*)d_in[1];
    const float* topo = (const float*)d_in[2];
    const float* Wl   = (const float*)d_in[3];
    const float* bl   = (const float*)d_in[4];
    const float* Wt   = (const float*)d_in[5];
    const float* bt   = (const float*)d_in[6];
    const float* attn = (const float*)d_in[7];
    const float* attt = (const float*)d_in[8];
    const float* bias = (const float*)d_in[9];
    float* out = (float*)d_out;

    char* p = (char*)d_ws;
    auto alloc = [&](size_t bytes) {
        char* r = p;
        p += (bytes + 511) & ~size_t(511);
        return r;
    };
    float*    wbuf      = (float*)   alloc((size_t)NN * HC * sizeof(float)); // 12.8 MB
    float*    es        = (float*)   alloc((size_t)NN * 2 * sizeof(float));  // 400 KB
    unsigned* cnt_row   = (unsigned*)alloc((size_t)NN * sizeof(unsigned));
    unsigned* offs      = (unsigned*)alloc((size_t)NN * sizeof(unsigned));
    unsigned* cursor    = (unsigned*)alloc((size_t)NN * sizeof(unsigned));
    unsigned* part_hist = (unsigned*)alloc((size_t)HG * (NPAD / 2) * sizeof(unsigned)); // 6.4 MB
    float*    part_sum  = (float*)   alloc(HG * 2 * sizeof(float));
    float*    gstat     = (float*)   alloc(4 * sizeof(float));
    unsigned* bsum      = (unsigned*)alloc(256 * sizeof(unsigned));
    float*    fused     = (float*)   alloc(512 * sizeof(float));
    // csr aliases part_hist: part_hist dead after scan1_k, csr born at scatter_k
    unsigned* csr       = part_hist;

    precompute_k<<<1, 256, 0, stream>>>(Wl, bl, Wt, bt, attn, attt, fused);
    score_k<<<782, 256, 0, stream>>>(x, topo, fused, es, out + (size_t)NN * HC);
    hist_sum_k<<<HG, 256, 0, stream>>>(eidx, es, part_hist, part_sum);
    scan1_k<<<SCAN_BLOCKS, 256, 0, stream>>>((const unsigned short*)part_hist,
                                             cnt_row, offs, bsum);
    sum_final_k<<<1, 64, 0, stream>>>(part_sum, gstat);
    scan2_k<<<SCAN_BLOCKS, 256, 0, stream>>>(bsum, offs, cursor);
    gemm_scale_k<<<(NN + 31) / 32, 256, 0, stream>>>(x, Wl, bl, es, gstat, wbuf);
    scatter_k<<<(EE + 255) / 256, 256, 0, stream>>>(eidx, cursor, csr);
    aggregate_k<<<(NN + 3) / 4, 256, 0, stream>>>(wbuf, csr, offs, cnt_row, bias, out);
}